// Round 3
// baseline (516.821 us; speedup 1.0000x reference)
//
#include <hip/hip_runtime.h>
#include <math.h>

#define BB 8
#define CIN 256
#define HW 4096
#define BHW 32768          // B*HW
#define COUT 256
#define KTOT 2304          // CIN*9
#define WS_N (BB*9*HW)     // 294912 floats per param array

// ws layout (floats):
//   0        sy   [WS_N]
//   WS_N     sx   [WS_N]
//   2*WS_N   m    [WS_N]
//   3*WS_N   w16  [294912 floats = 589824 bf16]  (tap-major [co][kk*256+c])
#define WOFF2_OFF (4*WS_N)            // 1179648: woff2 [256*9*28] = 64512 floats
#define PART_OFF  (WOFF2_OFF + 64512) // 1244160: partials [NS*27*BHW]
#define NEED2_BYTES ((size_t)(PART_OFF + 2*27*BHW) * 4)

typedef __bf16 bf16;
typedef __attribute__((ext_vector_type(8))) __bf16 bf16x8;
typedef __attribute__((ext_vector_type(4))) __bf16 bf16x4;
typedef __attribute__((ext_vector_type(4))) float f32x4;

// ---------------- wprep: w_off [27][256*9] -> woff2 [(c*9+t)*28 + j] ----------------
__global__ __launch_bounds__(256) void wprep_kernel(
    const float* __restrict__ w_off, float* __restrict__ woff2)
{
  const int c = blockIdx.x;
  const int tid = threadIdx.x;
  if (tid < 252) {                 // 9 taps * 28 slots
    int t = tid / 28, j = tid % 28;
    float v = (j < 27) ? w_off[(size_t)j * KTOT + c * 9 + t] : 0.f;
    woff2[((size_t)c * 9 + t) * 28 + j] = v;
  }
}

// ---------------- offconv: 256->27 conv; NS-way c-split ----------------
template<int NS>
__global__ __launch_bounds__(256) void offconv2_kernel(
    const float* __restrict__ x, const float* __restrict__ woff2,
    const float* __restrict__ b_off, float* __restrict__ ws)
{
  const int tid = threadIdx.x;
  const int bs  = blockIdx.x;
  const int st  = bs & 15;
  const int b   = (bs >> 4) & 7;
  const int s   = bs >> 7;                  // 0..NS-1
  const int pos = st * 256 + tid;
  const int ho  = pos >> 6, wo = pos & 63;
  const int c0  = s * (CIN / NS), c1 = c0 + CIN / NS;

  int   toff[9];
  float tvf[9];
#pragma unroll
  for (int t = 0; t < 9; ++t) {
    int ky = t / 3, kx = t % 3;
    int yy = ho - 1 + ky, xx = wo - 1 + kx;
    bool ok = ((unsigned)yy < 64u) && ((unsigned)xx < 64u);
    toff[t] = (min(max(yy, 0), 63)) * 64 + min(max(xx, 0), 63);
    tvf[t]  = ok ? 1.f : 0.f;
  }

  float a[27];
#pragma unroll
  for (int j = 0; j < 27; ++j) a[j] = 0.f;

  const float* xb = x + (size_t)b * CIN * HW;
#pragma unroll 2
  for (int c = c0; c < c1; ++c) {
    const float* xc = xb + (size_t)c * HW;
    float xv[9];
#pragma unroll
    for (int t = 0; t < 9; ++t) xv[t] = xc[toff[t]] * tvf[t];
    const float4* wr4 = (const float4*)(woff2 + (size_t)c * 252);
#pragma unroll
    for (int t = 0; t < 9; ++t) {
#pragma unroll
      for (int q = 0; q < 7; ++q) {
        float4 w4 = wr4[t * 7 + q];
        int j0 = q * 4;
        a[j0 + 0] = fmaf(w4.x, xv[t], a[j0 + 0]);
        a[j0 + 1] = fmaf(w4.y, xv[t], a[j0 + 1]);
        a[j0 + 2] = fmaf(w4.z, xv[t], a[j0 + 2]);
        if (j0 + 3 < 27) a[j0 + 3] = fmaf(w4.w, xv[t], a[j0 + 3]);
      }
    }
  }

  if (NS == 1) {
#pragma unroll
    for (int kk = 0; kk < 9; ++kk) {
      float syv = a[2 * kk]     + b_off[2 * kk]     + (float)(ho - 1 + kk / 3);
      float sxv = a[2 * kk + 1] + b_off[2 * kk + 1] + (float)(wo - 1 + kk % 3);
      float mv  = a[18 + kk]    + b_off[18 + kk];
      ws[(b * 9 + kk) * HW + pos]            = syv;
      ws[WS_N + (b * 9 + kk) * HW + pos]     = sxv;
      ws[2 * WS_N + (b * 9 + kk) * HW + pos] = 1.f / (1.f + expf(-mv));
    }
  } else {
    float* part = ws + PART_OFF + (size_t)s * 27 * BHW;
    const int bp = b * HW + pos;
#pragma unroll
    for (int j = 0; j < 27; ++j) part[(size_t)j * BHW + bp] = a[j];
  }
}

// ---------------- combine (NS=2): sum partials + bias + transform ----------------
__global__ __launch_bounds__(256) void combine_kernel(
    const float* __restrict__ b_off, float* __restrict__ ws)
{
  int gid = blockIdx.x * 256 + threadIdx.x;   // 9*BHW total
  int kk = gid >> 15, bp = gid & 32767;
  int b = bp >> 12, pos = bp & 4095;
  int ho = pos >> 6, wo = pos & 63;
  const float* p0 = ws + PART_OFF;
  const float* p1 = p0 + (size_t)27 * BHW;
  int jy = 2 * kk, jx = 2 * kk + 1, jm = 18 + kk;
  float syv = p0[(size_t)jy * BHW + bp] + p1[(size_t)jy * BHW + bp] + b_off[jy] + (float)(ho - 1 + kk / 3);
  float sxv = p0[(size_t)jx * BHW + bp] + p1[(size_t)jx * BHW + bp] + b_off[jx] + (float)(wo - 1 + kk % 3);
  float mv  = p0[(size_t)jm * BHW + bp] + p1[(size_t)jm * BHW + bp] + b_off[jm];
  ws[(b * 9 + kk) * HW + pos]            = syv;
  ws[WS_N + (b * 9 + kk) * HW + pos]     = sxv;
  ws[2 * WS_N + (b * 9 + kk) * HW + pos] = 1.f / (1.f + expf(-mv));
}

// ---------------- wconv: w_dcn -> bf16, tap-major permute ----------------
// w16[co][kk*256 + c] = w_dcn[co][c*9 + kk]
__global__ __launch_bounds__(256) void wconv_kernel(
    const float* __restrict__ w, bf16* __restrict__ o)
{
  const int co = blockIdx.x;
  const int c  = threadIdx.x;
#pragma unroll
  for (int kk = 0; kk < 9; ++kk)
    o[(size_t)co * KTOT + kk * 256 + c] = (bf16)w[(size_t)co * KTOT + c * 9 + kk];
}

// ---------------- dcn: bilinear gather + MFMA GEMM (tap-major K) ----------------
#define KSTEP 32
#define NK 72
#define AP 40

__global__ __launch_bounds__(512, 4) void dcn_mfma2_kernel(
    const float* __restrict__ x, const bf16* __restrict__ w16,
    const float* __restrict__ b_dcn, const float* __restrict__ ws,
    float* __restrict__ out)
{
  __shared__ bf16 A_lds[256 * AP];     // 20.5 KB
  __shared__ bf16 Bv_lds[64 * AP];     // 5.1 KB
  __shared__ int   poff0[576], poff1[576];
  __shared__ float pa0s[576], pa1s[576], pw0s[576], pw1s[576];

  const int tid  = threadIdx.x;
  const int b    = blockIdx.x >> 6;
  const int pos0 = (blockIdx.x & 63) * 64;

  // per-(kk,p) bilinear params: row bases + folded (validity,mask) weights
  for (int t = tid; t < 576; t += 512) {
    int kk = t >> 6, p = t & 63;
    int pos = pos0 + p;
    float sy = ws[(b * 9 + kk) * HW + pos];
    float sx = ws[WS_N + (b * 9 + kk) * HW + pos];
    float m  = ws[2 * WS_N + (b * 9 + kk) * HW + pos];
    float y0f = floorf(sy), x0f = floorf(sx);
    int y0 = (int)y0f, x0 = (int)x0f;
    float wy = sy - y0f, wx = sx - x0f;
    int ix0 = min(max(x0, 0), 63), ix1 = min(max(x0 + 1, 0), 63);
    int bx  = min(max(x0, 0), 62);
    float vx0 = (x0 >= 0  && x0 <= 63) ? 1.f : 0.f;
    float vx1 = (x0 >= -1 && x0 <= 62) ? 1.f : 0.f;
    float wx0 = (1.f - wx) * vx0, wx1 = wx * vx1;
    float a0 = (ix0 == bx     ? wx0 : 0.f) + (ix1 == bx     ? wx1 : 0.f);
    float a1 = (ix0 == bx + 1 ? wx0 : 0.f) + (ix1 == bx + 1 ? wx1 : 0.f);
    int rb0 = min(max(y0, 0), 63), rb1 = min(max(y0 + 1, 0), 63);
    float vy0 = (y0 >= 0  && y0 <= 63) ? 1.f : 0.f;
    float vy1 = (y0 >= -1 && y0 <= 62) ? 1.f : 0.f;
    poff0[t] = rb0 * 64 + bx;
    poff1[t] = rb1 * 64 + bx;
    pa0s[t] = a0; pa1s[t] = a1;
    pw0s[t] = (1.f - wy) * vy0 * m;
    pw1s[t] = wy * vy1 * m;
  }
  __syncthreads();

  const int lane = tid & 63, wid = tid >> 6;
  const int wr = wid >> 1, wc = wid & 1;
  const int lm = lane & 15, lk = lane >> 4;
  const int aco = tid & 255, ah = tid >> 8;
  const int gp = tid & 63, gg = tid >> 6;

  f32x4 acc[4][2];
#pragma unroll
  for (int a = 0; a < 4; ++a)
#pragma unroll
    for (int c = 0; c < 2; ++c)
      acc[a][c] = (f32x4){0.f, 0.f, 0.f, 0.f};

  const float* xb = x + (size_t)b * CIN * HW;
  const bf16* wrow = w16 + (size_t)aco * KTOT + ah * 16;

  // params in registers (kk=0)
  int   o0 = poff0[gp], o1 = poff1[gp];
  float pa0 = pa0s[gp], pa1 = pa1s[gp], pw0 = pw0s[gp], pw1 = pw1s[gp];

  uint4 ar0, ar1;
  float f00[4], f01[4], f10[4], f11[4];   // corner values, 4 channels

  // prologue: issue loads for ks=0
  ar0 = *(const uint4*)(wrow);
  ar1 = *(const uint4*)(wrow + 8);
  {
    const float* pc = xb + (size_t)(gg * 4) * HW;
#pragma unroll
    for (int e = 0; e < 4; ++e) {
      f00[e] = pc[o0]; f01[e] = pc[o0 + 1];
      f10[e] = pc[o1]; f11[e] = pc[o1 + 1];
      pc += HW;
    }
  }

  for (int ks = 0; ks < NK; ++ks) {
    // combine loaded corners into bf16 V (waits on vmcnt here)
    bf16x4 vv;
#pragma unroll
    for (int e = 0; e < 4; ++e) {
      float v = pw0 * fmaf(pa0, f00[e], pa1 * f01[e])
              + pw1 * fmaf(pa0, f10[e], pa1 * f11[e]);
      vv[e] = (bf16)v;
    }
    __syncthreads();            // previous step's fragment reads done
    *(uint4*)&A_lds[aco * AP + ah * 16]     = ar0;
    *(uint4*)&A_lds[aco * AP + ah * 16 + 8] = ar1;
    *(bf16x4*)&Bv_lds[gp * AP + gg * 4]     = vv;
    __syncthreads();            // tile ready

    // issue next step's loads (latency hides under ds_reads + MFMA)
    if (ks + 1 < NK) {
      const int ksn = ks + 1;
      if ((ksn & 7) == 0) {     // tap changes every 8 k-steps
        int idx = (ksn >> 3) * 64 + gp;
        o0 = poff0[idx]; o1 = poff1[idx];
        pa0 = pa0s[idx]; pa1 = pa1s[idx]; pw0 = pw0s[idx]; pw1 = pw1s[idx];
      }
      ar0 = *(const uint4*)(wrow + ksn * KSTEP);
      ar1 = *(const uint4*)(wrow + ksn * KSTEP + 8);
      const float* pc = xb + (size_t)(((ksn & 7) << 5) + (gg << 2)) * HW;
#pragma unroll
      for (int e = 0; e < 4; ++e) {
        f00[e] = pc[o0]; f01[e] = pc[o0 + 1];
        f10[e] = pc[o1]; f11[e] = pc[o1 + 1];
        pc += HW;
      }
    }

    // fragments + 8 MFMA
    bf16x8 af0 = *(const bf16x8*)&A_lds[(wr * 64 +  0 + lm) * AP + lk * 8];
    bf16x8 af1 = *(const bf16x8*)&A_lds[(wr * 64 + 16 + lm) * AP + lk * 8];
    bf16x8 af2 = *(const bf16x8*)&A_lds[(wr * 64 + 32 + lm) * AP + lk * 8];
    bf16x8 af3 = *(const bf16x8*)&A_lds[(wr * 64 + 48 + lm) * AP + lk * 8];
    bf16x8 bf0 = *(const bf16x8*)&Bv_lds[(wc * 32 +  0 + lm) * AP + lk * 8];
    bf16x8 bf1 = *(const bf16x8*)&Bv_lds[(wc * 32 + 16 + lm) * AP + lk * 8];
    acc[0][0] = __builtin_amdgcn_mfma_f32_16x16x32_bf16(af0, bf0, acc[0][0], 0, 0, 0);
    acc[0][1] = __builtin_amdgcn_mfma_f32_16x16x32_bf16(af0, bf1, acc[0][1], 0, 0, 0);
    acc[1][0] = __builtin_amdgcn_mfma_f32_16x16x32_bf16(af1, bf0, acc[1][0], 0, 0, 0);
    acc[1][1] = __builtin_amdgcn_mfma_f32_16x16x32_bf16(af1, bf1, acc[1][1], 0, 0, 0);
    acc[2][0] = __builtin_amdgcn_mfma_f32_16x16x32_bf16(af2, bf0, acc[2][0], 0, 0, 0);
    acc[2][1] = __builtin_amdgcn_mfma_f32_16x16x32_bf16(af2, bf1, acc[2][1], 0, 0, 0);
    acc[3][0] = __builtin_amdgcn_mfma_f32_16x16x32_bf16(af3, bf0, acc[3][0], 0, 0, 0);
    acc[3][1] = __builtin_amdgcn_mfma_f32_16x16x32_bf16(af3, bf1, acc[3][1], 0, 0, 0);
  }

  // epilogue: bias + store (C/D: col=lane&15, row=(lane>>4)*4+reg)
  const int pbase = pos0 + wc * 32;
#pragma unroll
  for (int fr = 0; fr < 4; ++fr) {
#pragma unroll
    for (int r = 0; r < 4; ++r) {
      int co = wr * 64 + fr * 16 + lk * 4 + r;
      float bias = b_dcn[co];
      float* orow = out + ((size_t)b * COUT + co) * HW + pbase;
      orow[lm]      = acc[fr][0][r] + bias;
      orow[16 + lm] = acc[fr][1][r] + bias;
    }
  }
}

extern "C" void kernel_launch(void* const* d_in, const int* in_sizes, int n_in,
                              void* d_out, int out_size, void* d_ws, size_t ws_size,
                              hipStream_t stream) {
  const float* x     = (const float*)d_in[0];
  const float* w_off = (const float*)d_in[1];
  const float* b_off = (const float*)d_in[2];
  const float* w_dcn = (const float*)d_in[3];
  const float* b_dcn = (const float*)d_in[4];
  float* out = (float*)d_out;
  float* ws  = (float*)d_ws;
  bf16* w16  = (bf16*)(ws + 3 * WS_N);
  float* woff2 = ws + WOFF2_OFF;

  wprep_kernel<<<256, 256, 0, stream>>>(w_off, woff2);
  if (ws_size >= NEED2_BYTES) {
    offconv2_kernel<2><<<2 * BB * 16, 256, 0, stream>>>(x, woff2, b_off, ws);
    combine_kernel<<<(9 * BHW) / 256, 256, 0, stream>>>(b_off, ws);
  } else {
    offconv2_kernel<1><<<BB * 16, 256, 0, stream>>>(x, woff2, b_off, ws);
  }
  wconv_kernel<<<COUT, 256, 0, stream>>>(w_dcn, w16);
  dcn_mfma2_kernel<<<BB * (HW / 64), 512, 0, stream>>>(x, w16, b_dcn, ws, out);
}

// Round 4
// 334.467 us; speedup vs baseline: 1.5452x; 1.5452x over previous
//
#include <hip/hip_runtime.h>
#include <math.h>

#define BB 8
#define CIN 256
#define HW 4096
#define BHW 32768          // B*HW
#define COUT 256
#define KTOT 2304          // CIN*9
#define WS_N (BB*9*HW)     // 294912 floats per param array

// ws layout (floats):
//   0        sy   [WS_N]
//   WS_N     sx   [WS_N]
//   2*WS_N   m    [WS_N]
//   3*WS_N   w16  [294912 floats = 589824 bf16]  (tap-major [co][kk*256+c])
#define WOFF2_OFF (4*WS_N)            // 1179648: woff2 [256*9*28] = 64512 floats
#define ACC_OFF   (WOFF2_OFF + 64512) // 1244160: accum [27][BHW]
#define ATOMIC_NEED ((size_t)(ACC_OFF + 27*BHW) * 4)

typedef __bf16 bf16;
typedef __attribute__((ext_vector_type(8))) __bf16 bf16x8;
typedef __attribute__((ext_vector_type(4))) __bf16 bf16x4;
typedef __attribute__((ext_vector_type(4))) float f32x4;
struct __attribute__((packed, aligned(4))) f2x { float x, y; };

// ---------------- wprep: w_off [27][256*9] -> woff2 [(c*9+t)*28 + j] ----------------
__global__ __launch_bounds__(256) void wprep_kernel(
    const float* __restrict__ w_off, float* __restrict__ woff2)
{
  const int c = blockIdx.x;
  const int tid = threadIdx.x;
  if (tid < 252) {
    int t = tid / 28, j = tid % 28;
    float v = (j < 27) ? w_off[(size_t)j * KTOT + c * 9 + t] : 0.f;
    woff2[((size_t)c * 9 + t) * 28 + j] = v;
  }
}

// ---------------- offconv: NS-way c-split, atomicAdd accumulate ----------------
template<int NS>
__global__ __launch_bounds__(256) void offconv_atom_kernel(
    const float* __restrict__ x, const float* __restrict__ woff2,
    float* __restrict__ accum)
{
  const int tid = threadIdx.x;
  const int bs  = blockIdx.x;
  const int st  = bs & 15;
  const int b   = (bs >> 4) & 7;
  const int s   = bs >> 7;                  // 0..NS-1
  const int pos = st * 256 + tid;
  const int ho  = pos >> 6, wo = pos & 63;
  const int c0  = s * (CIN / NS), c1 = c0 + CIN / NS;

  int   toff[9];
  float tvf[9];
#pragma unroll
  for (int t = 0; t < 9; ++t) {
    int ky = t / 3, kx = t % 3;
    int yy = ho - 1 + ky, xx = wo - 1 + kx;
    bool ok = ((unsigned)yy < 64u) && ((unsigned)xx < 64u);
    toff[t] = (min(max(yy, 0), 63)) * 64 + min(max(xx, 0), 63);
    tvf[t]  = ok ? 1.f : 0.f;
  }

  float a[27];
#pragma unroll
  for (int j = 0; j < 27; ++j) a[j] = 0.f;

  const float* xb = x + (size_t)b * CIN * HW;
  for (int c = c0; c < c1; ++c) {
    const float* xc = xb + (size_t)c * HW;
    float xv[9];
#pragma unroll
    for (int t = 0; t < 9; ++t) xv[t] = xc[toff[t]] * tvf[t];
    const float4* wr4 = (const float4*)(woff2 + (size_t)c * 252);
#pragma unroll
    for (int t = 0; t < 9; ++t) {
      float4 wb[7];
#pragma unroll
      for (int q = 0; q < 7; ++q) wb[q] = wr4[t * 7 + q];
#pragma unroll
      for (int q = 0; q < 7; ++q) {
        int j0 = q * 4;
        a[j0 + 0] = fmaf(wb[q].x, xv[t], a[j0 + 0]);
        a[j0 + 1] = fmaf(wb[q].y, xv[t], a[j0 + 1]);
        a[j0 + 2] = fmaf(wb[q].z, xv[t], a[j0 + 2]);
        if (j0 + 3 < 27) a[j0 + 3] = fmaf(wb[q].w, xv[t], a[j0 + 3]);
      }
    }
  }

  const int bp = b * HW + pos;
#pragma unroll
  for (int j = 0; j < 27; ++j)
    atomicAdd(&accum[(size_t)j * BHW + bp], a[j]);
}

// fallback (no accum buffer): NS=1 direct write
__global__ __launch_bounds__(256) void offconv_direct_kernel(
    const float* __restrict__ x, const float* __restrict__ woff2,
    const float* __restrict__ b_off, float* __restrict__ ws)
{
  const int tid = threadIdx.x;
  const int bs  = blockIdx.x;
  const int st  = bs & 15;
  const int b   = bs >> 4;
  const int pos = st * 256 + tid;
  const int ho  = pos >> 6, wo = pos & 63;

  int   toff[9];
  float tvf[9];
#pragma unroll
  for (int t = 0; t < 9; ++t) {
    int ky = t / 3, kx = t % 3;
    int yy = ho - 1 + ky, xx = wo - 1 + kx;
    bool ok = ((unsigned)yy < 64u) && ((unsigned)xx < 64u);
    toff[t] = (min(max(yy, 0), 63)) * 64 + min(max(xx, 0), 63);
    tvf[t]  = ok ? 1.f : 0.f;
  }
  float a[27];
#pragma unroll
  for (int j = 0; j < 27; ++j) a[j] = 0.f;
  const float* xb = x + (size_t)b * CIN * HW;
  for (int c = 0; c < CIN; ++c) {
    const float* xc = xb + (size_t)c * HW;
    float xv[9];
#pragma unroll
    for (int t = 0; t < 9; ++t) xv[t] = xc[toff[t]] * tvf[t];
    const float4* wr4 = (const float4*)(woff2 + (size_t)c * 252);
#pragma unroll
    for (int t = 0; t < 9; ++t) {
      float4 wb[7];
#pragma unroll
      for (int q = 0; q < 7; ++q) wb[q] = wr4[t * 7 + q];
#pragma unroll
      for (int q = 0; q < 7; ++q) {
        int j0 = q * 4;
        a[j0 + 0] = fmaf(wb[q].x, xv[t], a[j0 + 0]);
        a[j0 + 1] = fmaf(wb[q].y, xv[t], a[j0 + 1]);
        a[j0 + 2] = fmaf(wb[q].z, xv[t], a[j0 + 2]);
        if (j0 + 3 < 27) a[j0 + 3] = fmaf(wb[q].w, xv[t], a[j0 + 3]);
      }
    }
  }
#pragma unroll
  for (int kk = 0; kk < 9; ++kk) {
    float syv = a[2 * kk]     + b_off[2 * kk]     + (float)(ho - 1 + kk / 3);
    float sxv = a[2 * kk + 1] + b_off[2 * kk + 1] + (float)(wo - 1 + kk % 3);
    float mv  = a[18 + kk]    + b_off[18 + kk];
    ws[(b * 9 + kk) * HW + pos]            = syv;
    ws[WS_N + (b * 9 + kk) * HW + pos]     = sxv;
    ws[2 * WS_N + (b * 9 + kk) * HW + pos] = 1.f / (1.f + expf(-mv));
  }
}

// ---------------- combine: accum + bias -> sy/sx/m ----------------
__global__ __launch_bounds__(256) void combine_kernel(
    const float* __restrict__ b_off, float* __restrict__ ws)
{
  int gid = blockIdx.x * 256 + threadIdx.x;   // 9*BHW total
  int kk = gid >> 15, bp = gid & 32767;
  int b = bp >> 12, pos = bp & 4095;
  int ho = pos >> 6, wo = pos & 63;
  const float* acc = ws + ACC_OFF;
  int jy = 2 * kk, jx = 2 * kk + 1, jm = 18 + kk;
  float syv = acc[(size_t)jy * BHW + bp] + b_off[jy] + (float)(ho - 1 + kk / 3);
  float sxv = acc[(size_t)jx * BHW + bp] + b_off[jx] + (float)(wo - 1 + kk % 3);
  float mv  = acc[(size_t)jm * BHW + bp] + b_off[jm];
  ws[(b * 9 + kk) * HW + pos]            = syv;
  ws[WS_N + (b * 9 + kk) * HW + pos]     = sxv;
  ws[2 * WS_N + (b * 9 + kk) * HW + pos] = 1.f / (1.f + expf(-mv));
}

// ---------------- wconv: w_dcn -> bf16, tap-major permute ----------------
__global__ __launch_bounds__(256) void wconv_kernel(
    const float* __restrict__ w, bf16* __restrict__ o)
{
  const int co = blockIdx.x;
  const int c  = threadIdx.x;
#pragma unroll
  for (int kk = 0; kk < 9; ++kk)
    o[(size_t)co * KTOT + kk * 256 + c] = (bf16)w[(size_t)co * KTOT + c * 9 + kk];
}

// ---------------- dcn: bilinear gather + MFMA GEMM (tap-major K) ----------------
#define KSTEP 32
#define NK 72
#define AP 36

__global__ __launch_bounds__(512, 4) void dcn_mfma2_kernel(
    const float* __restrict__ x, const bf16* __restrict__ w16,
    const float* __restrict__ b_dcn, const float* __restrict__ ws,
    float* __restrict__ out)
{
  __shared__ bf16 A_lds[256 * AP];     // 18.4 KB
  __shared__ bf16 Bv_lds[64 * AP];     // 4.6 KB
  __shared__ int   poff0[576], poff1[576];
  __shared__ float pa0s[576], pa1s[576], pw0s[576], pw1s[576];

  const int tid  = threadIdx.x;
  const int b    = blockIdx.x >> 6;
  const int pos0 = (blockIdx.x & 63) * 64;

  for (int t = tid; t < 576; t += 512) {
    int kk = t >> 6, p = t & 63;
    int pos = pos0 + p;
    float sy = ws[(b * 9 + kk) * HW + pos];
    float sx = ws[WS_N + (b * 9 + kk) * HW + pos];
    float m  = ws[2 * WS_N + (b * 9 + kk) * HW + pos];
    float y0f = floorf(sy), x0f = floorf(sx);
    int y0 = (int)y0f, x0 = (int)x0f;
    float wy = sy - y0f, wx = sx - x0f;
    int ix0 = min(max(x0, 0), 63), ix1 = min(max(x0 + 1, 0), 63);
    int bx  = min(max(x0, 0), 62);
    float vx0 = (x0 >= 0  && x0 <= 63) ? 1.f : 0.f;
    float vx1 = (x0 >= -1 && x0 <= 62) ? 1.f : 0.f;
    float wx0 = (1.f - wx) * vx0, wx1 = wx * vx1;
    float a0 = (ix0 == bx     ? wx0 : 0.f) + (ix1 == bx     ? wx1 : 0.f);
    float a1 = (ix0 == bx + 1 ? wx0 : 0.f) + (ix1 == bx + 1 ? wx1 : 0.f);
    int rb0 = min(max(y0, 0), 63), rb1 = min(max(y0 + 1, 0), 63);
    float vy0 = (y0 >= 0  && y0 <= 63) ? 1.f : 0.f;
    float vy1 = (y0 >= -1 && y0 <= 62) ? 1.f : 0.f;
    poff0[t] = rb0 * 64 + bx;
    poff1[t] = rb1 * 64 + bx;
    pa0s[t] = a0; pa1s[t] = a1;
    pw0s[t] = (1.f - wy) * vy0 * m;
    pw1s[t] = wy * vy1 * m;
  }
  __syncthreads();

  const int lane = tid & 63, wid = tid >> 6;
  const int wr = wid >> 1, wc = wid & 1;
  const int lm = lane & 15, lk = lane >> 4;
  const int aco = tid & 255, ah = tid >> 8;
  const int gp = tid & 63, gg = tid >> 6;

  f32x4 acc[4][2];
#pragma unroll
  for (int a = 0; a < 4; ++a)
#pragma unroll
    for (int c = 0; c < 2; ++c)
      acc[a][c] = (f32x4){0.f, 0.f, 0.f, 0.f};

  const float* xb = x + (size_t)b * CIN * HW;
  const bf16* wrow = w16 + (size_t)aco * KTOT + ah * 16;

  int   o0 = poff0[gp], o1 = poff1[gp];
  float pa0 = pa0s[gp], pa1 = pa1s[gp], pw0 = pw0s[gp], pw1 = pw1s[gp];

  uint4 ar0, ar1;
  f2x r0[4], r1[4];   // (bx,bx+1) corner pairs, rows 0/1, 4 channels

  ar0 = *(const uint4*)(wrow);
  ar1 = *(const uint4*)(wrow + 8);
  {
    const float* pc = xb + (size_t)(gg * 4) * HW;
#pragma unroll
    for (int e = 0; e < 4; ++e) {
      r0[e] = *(const f2x*)(pc + o0);
      r1[e] = *(const f2x*)(pc + o1);
      pc += HW;
    }
  }

  for (int ks = 0; ks < NK; ++ks) {
    bf16x4 vv;
#pragma unroll
    for (int e = 0; e < 4; ++e) {
      float v = pw0 * fmaf(pa0, r0[e].x, pa1 * r0[e].y)
              + pw1 * fmaf(pa0, r1[e].x, pa1 * r1[e].y);
      vv[e] = (bf16)v;
    }
    __syncthreads();
    *(uint4*)&A_lds[aco * AP + ah * 16]     = ar0;
    *(uint4*)&A_lds[aco * AP + ah * 16 + 8] = ar1;
    *(bf16x4*)&Bv_lds[gp * AP + gg * 4]     = vv;
    __syncthreads();

    if (ks + 1 < NK) {
      const int ksn = ks + 1;
      if ((ksn & 7) == 0) {
        int idx = (ksn >> 3) * 64 + gp;
        o0 = poff0[idx]; o1 = poff1[idx];
        pa0 = pa0s[idx]; pa1 = pa1s[idx]; pw0 = pw0s[idx]; pw1 = pw1s[idx];
      }
      ar0 = *(const uint4*)(wrow + ksn * KSTEP);
      ar1 = *(const uint4*)(wrow + ksn * KSTEP + 8);
      const float* pc = xb + (size_t)(((ksn & 7) << 5) + (gg << 2)) * HW;
#pragma unroll
      for (int e = 0; e < 4; ++e) {
        r0[e] = *(const f2x*)(pc + o0);
        r1[e] = *(const f2x*)(pc + o1);
        pc += HW;
      }
    }

    bf16x8 af0 = *(const bf16x8*)&A_lds[(wr * 64 +  0 + lm) * AP + lk * 8];
    bf16x8 af1 = *(const bf16x8*)&A_lds[(wr * 64 + 16 + lm) * AP + lk * 8];
    bf16x8 af2 = *(const bf16x8*)&A_lds[(wr * 64 + 32 + lm) * AP + lk * 8];
    bf16x8 af3 = *(const bf16x8*)&A_lds[(wr * 64 + 48 + lm) * AP + lk * 8];
    bf16x8 bf0 = *(const bf16x8*)&Bv_lds[(wc * 32 +  0 + lm) * AP + lk * 8];
    bf16x8 bf1 = *(const bf16x8*)&Bv_lds[(wc * 32 + 16 + lm) * AP + lk * 8];
    acc[0][0] = __builtin_amdgcn_mfma_f32_16x16x32_bf16(af0, bf0, acc[0][0], 0, 0, 0);
    acc[0][1] = __builtin_amdgcn_mfma_f32_16x16x32_bf16(af0, bf1, acc[0][1], 0, 0, 0);
    acc[1][0] = __builtin_amdgcn_mfma_f32_16x16x32_bf16(af1, bf0, acc[1][0], 0, 0, 0);
    acc[1][1] = __builtin_amdgcn_mfma_f32_16x16x32_bf16(af1, bf1, acc[1][1], 0, 0, 0);
    acc[2][0] = __builtin_amdgcn_mfma_f32_16x16x32_bf16(af2, bf0, acc[2][0], 0, 0, 0);
    acc[2][1] = __builtin_amdgcn_mfma_f32_16x16x32_bf16(af2, bf1, acc[2][1], 0, 0, 0);
    acc[3][0] = __builtin_amdgcn_mfma_f32_16x16x32_bf16(af3, bf0, acc[3][0], 0, 0, 0);
    acc[3][1] = __builtin_amdgcn_mfma_f32_16x16x32_bf16(af3, bf1, acc[3][1], 0, 0, 0);
  }

  const int pbase = pos0 + wc * 32;
#pragma unroll
  for (int fr = 0; fr < 4; ++fr) {
#pragma unroll
    for (int r = 0; r < 4; ++r) {
      int co = wr * 64 + fr * 16 + lk * 4 + r;
      float bias = b_dcn[co];
      float* orow = out + ((size_t)b * COUT + co) * HW + pbase;
      orow[lm]      = acc[fr][0][r] + bias;
      orow[16 + lm] = acc[fr][1][r] + bias;
    }
  }
}

extern "C" void kernel_launch(void* const* d_in, const int* in_sizes, int n_in,
                              void* d_out, int out_size, void* d_ws, size_t ws_size,
                              hipStream_t stream) {
  const float* x     = (const float*)d_in[0];
  const float* w_off = (const float*)d_in[1];
  const float* b_off = (const float*)d_in[2];
  const float* w_dcn = (const float*)d_in[3];
  const float* b_dcn = (const float*)d_in[4];
  float* out = (float*)d_out;
  float* ws  = (float*)d_ws;
  bf16* w16  = (bf16*)(ws + 3 * WS_N);
  float* woff2 = ws + WOFF2_OFF;

  wprep_kernel<<<256, 256, 0, stream>>>(w_off, woff2);
  if (ws_size >= ATOMIC_NEED) {
    hipMemsetAsync(ws + ACC_OFF, 0, (size_t)27 * BHW * 4, stream);
    offconv_atom_kernel<8><<<8 * BB * 16, 256, 0, stream>>>(x, woff2, ws + ACC_OFF);
    combine_kernel<<<(9 * BHW) / 256, 256, 0, stream>>>(b_off, ws);
  } else {
    offconv_direct_kernel<<<BB * 16, 256, 0, stream>>>(x, woff2, b_off, ws);
  }
  wconv_kernel<<<COUT, 256, 0, stream>>>(w_dcn, w16);
  dcn_mfma2_kernel<<<BB * (HW / 64), 512, 0, stream>>>(x, w16, b_dcn, ws, out);
}